// Round 1
// baseline (227.322 us; speedup 1.0000x reference)
//
#include <hip/hip_runtime.h>

#define SS 512
#define BB 32
#define TQ 128
#define TK 32
#define WROW (TQ + 4)   // pad so staged-transpose writes don't all hit one bank

// ---------------------------------------------------------------------------
// Kernel A: y = x everywhere; the GEMM kernel overwrites the p+c < S triangle.
// 8388608 floats = 2097152 float4 -> 8192 blocks x 256 threads, exact.
// ---------------------------------------------------------------------------
__global__ __launch_bounds__(256) void copy_x_kernel(const float* __restrict__ x,
                                                     float* __restrict__ y) {
    size_t idx = (size_t)blockIdx.x * 256 + threadIdx.x;
    reinterpret_cast<float4*>(y)[idx] = reinterpret_cast<const float4*>(x)[idx];
}

// ---------------------------------------------------------------------------
// Kernel B: one block = one i (anti-diagonal) x one 128-wide q tile.
//   out[b,i,q] = sum_{r<=i} x[b,r,i-r] * W[i,q,r] + bias[i,q]   (q <= i only)
//   y[b,q,i-q] = out[b,i,q]
// 256 threads: thread (bg=tid>>5, qg=tid&31) owns 4 batches x 4 q -> 16 acc.
// ---------------------------------------------------------------------------
__global__ __launch_bounds__(256) void diag_gemm_kernel(const float* __restrict__ x,
                                                        const float* __restrict__ W,
                                                        const float* __restrict__ bias,
                                                        float* __restrict__ y) {
    const int i  = (SS - 1) - (int)blockIdx.y;   // big-K blocks first (tail)
    const int q0 = (int)blockIdx.x * TQ;
    if (q0 > i) return;                           // uniform early exit

    __shared__ float Ds[TK][BB];      // D[b, r0+rr]      at Ds[rr][b]
    __shared__ float Ws[TK][WROW];    // W[i, q0+qq, r0+rr] at Ws[rr][qq]

    const int tid = (int)threadIdx.x;
    const int qg  = tid & 31;   // q group: 4 consecutive q
    const int bg  = tid >> 5;   // b group: 4 consecutive b

    float acc[4][4];
#pragma unroll
    for (int a = 0; a < 4; ++a)
#pragma unroll
        for (int c = 0; c < 4; ++c) acc[a][c] = 0.0f;

    const float* Wi = W + (size_t)i * SS * SS;

    for (int r0 = 0; r0 <= i; r0 += TK) {
        __syncthreads();   // protect LDS from previous iteration's readers

        // ---- stage D: 32 rr x 32 b, one float4 (4 batches) per thread ----
        {
            const int rr = tid >> 3;
            const int b4 = (tid & 7) * 4;
            const int r  = r0 + rr;
            float4 dv = make_float4(0.f, 0.f, 0.f, 0.f);
            if (r <= i) {
                const int col = i - r;   // >= 0
                dv.x = x[((size_t)(b4 + 0) * SS + r) * SS + col];
                dv.y = x[((size_t)(b4 + 1) * SS + r) * SS + col];
                dv.z = x[((size_t)(b4 + 2) * SS + r) * SS + col];
                dv.w = x[((size_t)(b4 + 3) * SS + r) * SS + col];
            }
            *reinterpret_cast<float4*>(&Ds[rr][b4]) = dv;
        }

        // ---- stage W tile transposed: read rows along r, write Ws[rr][qq] ----
#pragma unroll
        for (int l = 0; l < 4; ++l) {
            const int idx = tid + 256 * l;
            const int qL  = idx >> 3;        // 0..127
            const int rc  = idx & 7;         // r chunk of 4
            const int r   = r0 + rc * 4;
            const float* wp = Wi + (size_t)(q0 + qL) * SS;
            float4 wv;
            if (r + 3 < SS) {
                wv = *reinterpret_cast<const float4*>(wp + r);
            } else {           // clamp: D is zero there, value irrelevant but must be finite
                wv.x = wp[min(r + 0, SS - 1)];
                wv.y = wp[min(r + 1, SS - 1)];
                wv.z = wp[min(r + 2, SS - 1)];
                wv.w = wp[min(r + 3, SS - 1)];
            }
            Ws[rc * 4 + 0][qL] = wv.x;
            Ws[rc * 4 + 1][qL] = wv.y;
            Ws[rc * 4 + 2][qL] = wv.z;
            Ws[rc * 4 + 3][qL] = wv.w;
        }
        __syncthreads();

        // ---- compute: 32 K-steps, 2x ds_read_b128 + 16 fma per step ----
#pragma unroll
        for (int rr = 0; rr < TK; ++rr) {
            const float4 d4 = *reinterpret_cast<const float4*>(&Ds[rr][bg * 4]);
            const float4 w4 = *reinterpret_cast<const float4*>(&Ws[rr][qg * 4]);
            acc[0][0] = fmaf(d4.x, w4.x, acc[0][0]);
            acc[0][1] = fmaf(d4.x, w4.y, acc[0][1]);
            acc[0][2] = fmaf(d4.x, w4.z, acc[0][2]);
            acc[0][3] = fmaf(d4.x, w4.w, acc[0][3]);
            acc[1][0] = fmaf(d4.y, w4.x, acc[1][0]);
            acc[1][1] = fmaf(d4.y, w4.y, acc[1][1]);
            acc[1][2] = fmaf(d4.y, w4.z, acc[1][2]);
            acc[1][3] = fmaf(d4.y, w4.w, acc[1][3]);
            acc[2][0] = fmaf(d4.z, w4.x, acc[2][0]);
            acc[2][1] = fmaf(d4.z, w4.y, acc[2][1]);
            acc[2][2] = fmaf(d4.z, w4.z, acc[2][2]);
            acc[2][3] = fmaf(d4.z, w4.w, acc[2][3]);
            acc[3][0] = fmaf(d4.w, w4.x, acc[3][0]);
            acc[3][1] = fmaf(d4.w, w4.y, acc[3][1]);
            acc[3][2] = fmaf(d4.w, w4.z, acc[3][2]);
            acc[3][3] = fmaf(d4.w, w4.w, acc[3][3]);
        }
    }

    // ---- epilogue: add bias, scatter to y[b, q, i-q] for q <= i ----
    const int qb = q0 + qg * 4;
    const float4 bv = *reinterpret_cast<const float4*>(bias + (size_t)i * SS + qb);
    const float bvals[4] = {bv.x, bv.y, bv.z, bv.w};
#pragma unroll
    for (int bi = 0; bi < 4; ++bi) {
        const int b = bg * 4 + bi;
        float* yb = y + (size_t)b * SS * SS;
#pragma unroll
        for (int qi = 0; qi < 4; ++qi) {
            const int q = qb + qi;
            if (q <= i) {
                yb[(size_t)q * SS + (i - q)] = acc[bi][qi] + bvals[qi];
            }
        }
    }
}

extern "C" void kernel_launch(void* const* d_in, const int* in_sizes, int n_in,
                              void* d_out, int out_size, void* d_ws, size_t ws_size,
                              hipStream_t stream) {
    const float* x    = (const float*)d_in[0];
    const float* W    = (const float*)d_in[1];
    const float* bias = (const float*)d_in[2];
    float* y          = (float*)d_out;

    copy_x_kernel<<<dim3(8192), dim3(256), 0, stream>>>(x, y);

    dim3 grid(SS / TQ, SS);   // x: 4 q-tiles, y: 512 anti-diagonals
    diag_gemm_kernel<<<grid, dim3(256), 0, stream>>>(x, W, bias, y);
}

// Round 2
// 172.735 us; speedup vs baseline: 1.3160x; 1.3160x over previous
//
#include <hip/hip_runtime.h>
#include <hip/hip_bf16.h>
#include <stdint.h>

#define SS 512
#define BB 32
#define TQ 128

typedef __bf16 bf16;
typedef __attribute__((ext_vector_type(8))) __bf16 bf16x8;
typedef __attribute__((ext_vector_type(4))) float f32x4;

// ---------------------------------------------------------------------------
// Kernel A: y = x everywhere; the GEMM kernel overwrites the q <= i triangle.
// ---------------------------------------------------------------------------
__global__ __launch_bounds__(256) void copy_x_kernel(const float* __restrict__ x,
                                                     float* __restrict__ y) {
    size_t idx = (size_t)blockIdx.x * 256 + threadIdx.x;
    reinterpret_cast<float4*>(y)[idx] = reinterpret_cast<const float4*>(x)[idx];
}

// ---------------------------------------------------------------------------
// Gather: D2[rb][b][i] (uint4 = 8 bf16, e-th elem = D[b, i, r=rb*8+e])
//   D[b,i,r] = x[b, r, i-r] if r <= i else 0
// Block (rb, b): stage 8 x-rows in LDS (coalesced read), anti-diag gather from
// LDS, fully-coalesced 16B/lane writes.
// ---------------------------------------------------------------------------
__global__ __launch_bounds__(256) void gather_kernel(const float* __restrict__ x,
                                                     uint4* __restrict__ D2) {
    const int rb = blockIdx.x;   // 0..63
    const int b  = blockIdx.y;   // 0..31
    __shared__ float xs[8][516];  // pad 516 to spread banks

    const int t = threadIdx.x;
    const float* xb = x + ((size_t)b * SS + rb * 8) * SS;
#pragma unroll
    for (int k = 0; k < 4; ++k) {
        int task = t + 256 * k;          // 1024 float4 tasks = 8 rows x 128
        int c4 = task & 127;
        int e  = task >> 7;
        float4 v = *reinterpret_cast<const float4*>(xb + (size_t)e * SS + c4 * 4);
        *reinterpret_cast<float4*>(&xs[e][c4 * 4]) = v;
    }
    __syncthreads();

    const int r0 = rb * 8;
#pragma unroll
    for (int k = 0; k < 2; ++k) {
        int i = t + 256 * k;             // 0..511
        bf16x8 pack;
#pragma unroll
        for (int e = 0; e < 8; ++e) {
            int c  = i - (r0 + e);
            int cc = c < 0 ? 0 : c;      // clamp so LDS read stays in-bounds
            float v = xs[e][cc];
            pack[e] = (c >= 0) ? (bf16)v : (bf16)0.0f;
        }
        D2[((size_t)rb * BB + b) * SS + i] = __builtin_bit_cast(uint4, pack);
    }
}

// ---------------------------------------------------------------------------
// MFMA GEMM: block = (i via XCD swizzle, q-tile of 128), 256 threads = 4 waves.
//   out[b,i,q] = sum_r D[b,i,r]*W[i,q,r] + bias[i,q], scatter y[b,q,i-q].
// Wave w owns frags f = w, w+4 (q = q0 + f*16 + lane15). A-frags direct from
// global D2 (L1-shared across waves); B staged f32->bf16 in LDS.
// ---------------------------------------------------------------------------
__global__ __launch_bounds__(256) void mfma_gemm_kernel(const uint4* __restrict__ D2,
                                                        const float* __restrict__ W,
                                                        const float* __restrict__ bias,
                                                        float* __restrict__ y) {
    // XCD-contiguous i: consecutive dispatch idx -> XCD round-robin, so give
    // XCD x the i-range [x*64, x*64+64). Reverse so heavy (large-i) blocks go first.
    const int bid = (int)blockIdx.x;                 // 0..511
    const int swz = (bid & 7) * 64 + (bid >> 3);
    const int i   = (SS - 1) - swz;
    const int q0  = (int)blockIdx.y * TQ;
    if (q0 > i) return;

    const int qmax = ((i >> 4) + 1) * 16;            // q padded to 16
    const int qhi  = min(qmax - q0, TQ);             // rows staged in this tile
    const int nk   = (i >> 5) + 1;                   // K-steps of 32

    __shared__ bf16 Bs[TQ][40];                      // row pitch 40 (80B) kills conflicts

    const int t    = (int)threadIdx.x;
    const int lane = t & 63;
    const int w    = t >> 6;                         // wave 0..3
    const int l15  = lane & 15;
    const int lg   = lane >> 4;                      // 0..3

    f32x4 acc[2][2];                                 // [n-frag][m-frag]
#pragma unroll
    for (int n = 0; n < 2; ++n)
#pragma unroll
        for (int m = 0; m < 2; ++m) acc[n][m] = (f32x4)0.0f;

    const float* Wi  = W + (size_t)i * SS * SS;
    const uint4* D2i = D2 + i;                       // +(rb*32+b)*512 per frag-reg

    for (int kk = 0; kk < nk; ++kk) {
        const int r0 = kk * 32;
        __syncthreads();                             // protect Bs readers

        // stage W[q0..q0+qhi) rows, 32 f32 each -> bf16; 4 chunk-tasks/row
#pragma unroll
        for (int s = 0; s < 2; ++s) {
            int task = t + 256 * s;
            if (task < qhi * 4) {
                int qq = task >> 2;
                int ch = task & 3;
                const float* wp = Wi + (size_t)(q0 + qq) * SS + r0 + ch * 8;
                float4 v0 = *reinterpret_cast<const float4*>(wp);
                float4 v1 = *reinterpret_cast<const float4*>(wp + 4);
                bf16x8 pk;
                pk[0] = (bf16)v0.x; pk[1] = (bf16)v0.y; pk[2] = (bf16)v0.z; pk[3] = (bf16)v0.w;
                pk[4] = (bf16)v1.x; pk[5] = (bf16)v1.y; pk[6] = (bf16)v1.z; pk[7] = (bf16)v1.w;
                *reinterpret_cast<uint4*>(&Bs[qq][ch * 8]) = __builtin_bit_cast(uint4, pk);
            }
        }

        // A-frags from global (no LDS dep -> overlaps barrier); lane: b=l15(+16), rb=r0/8+lg
        const uint4 a0 = D2i[(size_t)(((r0 >> 3) + lg) * BB + l15) * SS];
        const uint4 a1 = D2i[(size_t)(((r0 >> 3) + lg) * BB + 16 + l15) * SS];

        __syncthreads();                             // Bs ready

        const bf16x8 aa0 = __builtin_bit_cast(bf16x8, a0);
        const bf16x8 aa1 = __builtin_bit_cast(bf16x8, a1);
#pragma unroll
        for (int n = 0; n < 2; ++n) {
            const int f  = n * 4 + w;
            const int qf = q0 + f * 16;
            if (qf <= i) {                           // wave-uniform
                uint4 bv = *reinterpret_cast<const uint4*>(&Bs[f * 16 + l15][lg * 8]);
                bf16x8 bb = __builtin_bit_cast(bf16x8, bv);
                acc[n][0] = __builtin_amdgcn_mfma_f32_16x16x32_bf16(aa0, bb, acc[n][0], 0, 0, 0);
                acc[n][1] = __builtin_amdgcn_mfma_f32_16x16x32_bf16(aa1, bb, acc[n][1], 0, 0, 0);
            }
        }
    }

    // epilogue: C/D layout col=lane&15 (q), row=(lane>>4)*4+reg (b)
#pragma unroll
    for (int n = 0; n < 2; ++n) {
        const int f  = n * 4 + w;
        const int qf = q0 + f * 16;
        if (qf <= i) {
            const int q  = qf + l15;
            const bool ok = (q <= i);
            const float bv = bias[(size_t)i * SS + q];   // q < 512 always
#pragma unroll
            for (int m = 0; m < 2; ++m) {
#pragma unroll
                for (int v = 0; v < 4; ++v) {
                    const int b = m * 16 + lg * 4 + v;
                    if (ok) y[((size_t)b * SS + q) * SS + (i - q)] = acc[n][m][v] + bv;
                }
            }
        }
    }
}

// ---------------------------------------------------------------------------
// Fallback (round-1 f32 kernel) in case ws_size < 16.8 MB.
// ---------------------------------------------------------------------------
#define FTK 32
#define FWROW (TQ + 4)
__global__ __launch_bounds__(256) void diag_gemm_fallback(const float* __restrict__ x,
                                                          const float* __restrict__ W,
                                                          const float* __restrict__ bias,
                                                          float* __restrict__ y) {
    const int i  = (SS - 1) - (int)blockIdx.y;
    const int q0 = (int)blockIdx.x * TQ;
    if (q0 > i) return;
    __shared__ float Ds[FTK][BB];
    __shared__ float Ws[FTK][FWROW];
    const int tid = (int)threadIdx.x;
    const int qg  = tid & 31;
    const int bg  = tid >> 5;
    float acc[4][4];
#pragma unroll
    for (int a = 0; a < 4; ++a)
#pragma unroll
        for (int c = 0; c < 4; ++c) acc[a][c] = 0.0f;
    const float* Wi = W + (size_t)i * SS * SS;
    for (int r0 = 0; r0 <= i; r0 += FTK) {
        __syncthreads();
        {
            const int rr = tid >> 3;
            const int b4 = (tid & 7) * 4;
            const int r  = r0 + rr;
            float4 dv = make_float4(0.f, 0.f, 0.f, 0.f);
            if (r <= i) {
                const int col = i - r;
                dv.x = x[((size_t)(b4 + 0) * SS + r) * SS + col];
                dv.y = x[((size_t)(b4 + 1) * SS + r) * SS + col];
                dv.z = x[((size_t)(b4 + 2) * SS + r) * SS + col];
                dv.w = x[((size_t)(b4 + 3) * SS + r) * SS + col];
            }
            *reinterpret_cast<float4*>(&Ds[rr][b4]) = dv;
        }
#pragma unroll
        for (int l = 0; l < 4; ++l) {
            const int idx = tid + 256 * l;
            const int qL  = idx >> 3;
            const int rc  = idx & 7;
            const int r   = r0 + rc * 4;
            const float* wp = Wi + (size_t)(q0 + qL) * SS;
            float4 wv;
            if (r + 3 < SS) {
                wv = *reinterpret_cast<const float4*>(wp + r);
            } else {
                wv.x = wp[min(r + 0, SS - 1)];
                wv.y = wp[min(r + 1, SS - 1)];
                wv.z = wp[min(r + 2, SS - 1)];
                wv.w = wp[min(r + 3, SS - 1)];
            }
            Ws[rc * 4 + 0][qL] = wv.x;
            Ws[rc * 4 + 1][qL] = wv.y;
            Ws[rc * 4 + 2][qL] = wv.z;
            Ws[rc * 4 + 3][qL] = wv.w;
        }
        __syncthreads();
#pragma unroll
        for (int rr = 0; rr < FTK; ++rr) {
            const float4 d4 = *reinterpret_cast<const float4*>(&Ds[rr][bg * 4]);
            const float4 w4 = *reinterpret_cast<const float4*>(&Ws[rr][qg * 4]);
            acc[0][0] = fmaf(d4.x, w4.x, acc[0][0]); acc[0][1] = fmaf(d4.x, w4.y, acc[0][1]);
            acc[0][2] = fmaf(d4.x, w4.z, acc[0][2]); acc[0][3] = fmaf(d4.x, w4.w, acc[0][3]);
            acc[1][0] = fmaf(d4.y, w4.x, acc[1][0]); acc[1][1] = fmaf(d4.y, w4.y, acc[1][1]);
            acc[1][2] = fmaf(d4.y, w4.z, acc[1][2]); acc[1][3] = fmaf(d4.y, w4.w, acc[1][3]);
            acc[2][0] = fmaf(d4.z, w4.x, acc[2][0]); acc[2][1] = fmaf(d4.z, w4.y, acc[2][1]);
            acc[2][2] = fmaf(d4.z, w4.z, acc[2][2]); acc[2][3] = fmaf(d4.z, w4.w, acc[2][3]);
            acc[3][0] = fmaf(d4.w, w4.x, acc[3][0]); acc[3][1] = fmaf(d4.w, w4.y, acc[3][1]);
            acc[3][2] = fmaf(d4.w, w4.z, acc[3][2]); acc[3][3] = fmaf(d4.w, w4.w, acc[3][3]);
        }
    }
    const int qb = q0 + qg * 4;
    const float4 bv = *reinterpret_cast<const float4*>(bias + (size_t)i * SS + qb);
    const float bvals[4] = {bv.x, bv.y, bv.z, bv.w};
#pragma unroll
    for (int bi = 0; bi < 4; ++bi) {
        const int b = bg * 4 + bi;
        float* yb = y + (size_t)b * SS * SS;
#pragma unroll
        for (int qi = 0; qi < 4; ++qi) {
            const int q = qb + qi;
            if (q <= i) yb[(size_t)q * SS + (i - q)] = acc[bi][qi] + bvals[qi];
        }
    }
}

extern "C" void kernel_launch(void* const* d_in, const int* in_sizes, int n_in,
                              void* d_out, int out_size, void* d_ws, size_t ws_size,
                              hipStream_t stream) {
    const float* x    = (const float*)d_in[0];
    const float* W    = (const float*)d_in[1];
    const float* bias = (const float*)d_in[2];
    float* y          = (float*)d_out;

    const size_t D2_bytes = (size_t)64 * BB * SS * 16;   // 16.78 MB

    copy_x_kernel<<<dim3(8192), dim3(256), 0, stream>>>(x, y);

    if (ws_size >= D2_bytes) {
        uint4* D2 = (uint4*)d_ws;
        gather_kernel<<<dim3(64, 32), dim3(256), 0, stream>>>(x, D2);
        mfma_gemm_kernel<<<dim3(512, 4), dim3(256), 0, stream>>>(D2, W, bias, y);
    } else {
        diag_gemm_fallback<<<dim3(SS / TQ, SS), dim3(256), 0, stream>>>(x, W, bias, y);
    }
}

// Round 3
// 146.129 us; speedup vs baseline: 1.5556x; 1.1821x over previous
//
#include <hip/hip_runtime.h>
#include <hip/hip_bf16.h>
#include <stdint.h>

#define SS 512
#define BB 32
#define TQ 128

typedef __bf16 bf16;
typedef __attribute__((ext_vector_type(8))) __bf16 bf16x8;
typedef __attribute__((ext_vector_type(4))) float f32x4;

// ---------------------------------------------------------------------------
// Kernel A (fallback paths only): y = x everywhere.
// ---------------------------------------------------------------------------
__global__ __launch_bounds__(256) void copy_x_kernel(const float* __restrict__ x,
                                                     float* __restrict__ y) {
    size_t idx = (size_t)blockIdx.x * 256 + threadIdx.x;
    reinterpret_cast<float4*>(y)[idx] = reinterpret_cast<const float4*>(x)[idx];
}

// ---------------------------------------------------------------------------
// Gather: D2[rb][b][i] (uint4 = 8 bf16, e-th elem = D[b, i, r=rb*8+e])
//   D[b,i,r] = x[b, r, i-r] if r <= i else 0
// ---------------------------------------------------------------------------
__global__ __launch_bounds__(256) void gather_kernel(const float* __restrict__ x,
                                                     uint4* __restrict__ D2) {
    const int rb = blockIdx.x;   // 0..63
    const int b  = blockIdx.y;   // 0..31
    __shared__ float xs[8][516];

    const int t = threadIdx.x;
    const float* xb = x + ((size_t)b * SS + rb * 8) * SS;
#pragma unroll
    for (int k = 0; k < 4; ++k) {
        int task = t + 256 * k;
        int c4 = task & 127;
        int e  = task >> 7;
        float4 v = *reinterpret_cast<const float4*>(xb + (size_t)e * SS + c4 * 4);
        *reinterpret_cast<float4*>(&xs[e][c4 * 4]) = v;
    }
    __syncthreads();

    const int r0 = rb * 8;
#pragma unroll
    for (int k = 0; k < 2; ++k) {
        int i = t + 256 * k;
        bf16x8 pack;
#pragma unroll
        for (int e = 0; e < 8; ++e) {
            int c  = i - (r0 + e);
            int cc = c < 0 ? 0 : c;
            float v = xs[e][cc];
            pack[e] = (c >= 0) ? (bf16)v : (bf16)0.0f;
        }
        D2[((size_t)rb * BB + b) * SS + i] = __builtin_bit_cast(uint4, pack);
    }
}

// ---------------------------------------------------------------------------
// MFMA GEMM. WRITE_O=1: out = O[b][i][q] coalesced (shear kernel finishes).
//           WRITE_O=0: out = y, direct anti-diagonal scatter (fallback).
// ---------------------------------------------------------------------------
template <int WRITE_O>
__global__ __launch_bounds__(256) void mfma_gemm_kernel(const uint4* __restrict__ D2,
                                                        const float* __restrict__ W,
                                                        const float* __restrict__ bias,
                                                        float* __restrict__ out) {
    const int bid = (int)blockIdx.x;                 // XCD-contiguous i ranges
    const int swz = (bid & 7) * 64 + (bid >> 3);
    const int i   = (SS - 1) - swz;
    const int q0  = (int)blockIdx.y * TQ;
    if (q0 > i) return;

    const int qmax = ((i >> 4) + 1) * 16;
    const int qhi  = min(qmax - q0, TQ);
    const int nk   = (i >> 5) + 1;

    __shared__ bf16 Bs[TQ][40];

    const int t    = (int)threadIdx.x;
    const int lane = t & 63;
    const int w    = t >> 6;
    const int l15  = lane & 15;
    const int lg   = lane >> 4;

    f32x4 acc[2][2];
#pragma unroll
    for (int n = 0; n < 2; ++n)
#pragma unroll
        for (int m = 0; m < 2; ++m) acc[n][m] = (f32x4)0.0f;

    const float* Wi  = W + (size_t)i * SS * SS;
    const uint4* D2i = D2 + i;

    for (int kk = 0; kk < nk; ++kk) {
        const int r0 = kk * 32;
        __syncthreads();

#pragma unroll
        for (int s = 0; s < 2; ++s) {
            int task = t + 256 * s;
            if (task < qhi * 4) {
                int qq = task >> 2;
                int ch = task & 3;
                const float* wp = Wi + (size_t)(q0 + qq) * SS + r0 + ch * 8;
                float4 v0 = *reinterpret_cast<const float4*>(wp);
                float4 v1 = *reinterpret_cast<const float4*>(wp + 4);
                bf16x8 pk;
                pk[0] = (bf16)v0.x; pk[1] = (bf16)v0.y; pk[2] = (bf16)v0.z; pk[3] = (bf16)v0.w;
                pk[4] = (bf16)v1.x; pk[5] = (bf16)v1.y; pk[6] = (bf16)v1.z; pk[7] = (bf16)v1.w;
                *reinterpret_cast<uint4*>(&Bs[qq][ch * 8]) = __builtin_bit_cast(uint4, pk);
            }
        }

        const uint4 a0 = D2i[(size_t)(((r0 >> 3) + lg) * BB + l15) * SS];
        const uint4 a1 = D2i[(size_t)(((r0 >> 3) + lg) * BB + 16 + l15) * SS];

        __syncthreads();

        const bf16x8 aa0 = __builtin_bit_cast(bf16x8, a0);
        const bf16x8 aa1 = __builtin_bit_cast(bf16x8, a1);
#pragma unroll
        for (int n = 0; n < 2; ++n) {
            const int f  = n * 4 + w;
            const int qf = q0 + f * 16;
            if (qf <= i) {
                uint4 bv = *reinterpret_cast<const uint4*>(&Bs[f * 16 + l15][lg * 8]);
                bf16x8 bb = __builtin_bit_cast(bf16x8, bv);
                acc[n][0] = __builtin_amdgcn_mfma_f32_16x16x32_bf16(aa0, bb, acc[n][0], 0, 0, 0);
                acc[n][1] = __builtin_amdgcn_mfma_f32_16x16x32_bf16(aa1, bb, acc[n][1], 0, 0, 0);
            }
        }
    }

    // C/D layout: col(q)=lane&15, row(b)=(lane>>4)*4+reg
#pragma unroll
    for (int n = 0; n < 2; ++n) {
        const int f  = n * 4 + w;
        const int qf = q0 + f * 16;
        if (qf <= i) {
            const int q  = qf + l15;
            const float bv = bias[(size_t)i * SS + q];
            if (WRITE_O) {
#pragma unroll
                for (int m = 0; m < 2; ++m)
#pragma unroll
                    for (int v = 0; v < 4; ++v) {
                        const int b = m * 16 + lg * 4 + v;
                        out[((size_t)b * SS + i) * SS + q] = acc[n][m][v] + bv;
                    }
            } else {
                const bool ok = (q <= i);
#pragma unroll
                for (int m = 0; m < 2; ++m)
#pragma unroll
                    for (int v = 0; v < 4; ++v) {
                        const int b = m * 16 + lg * 4 + v;
                        if (ok) out[((size_t)b * SS + q) * SS + (i - q)] = acc[n][m][v] + bv;
                    }
            }
        }
    }
}

// ---------------------------------------------------------------------------
// Shear: y[b][q][c] = (q+c < S) ? O[b][q+c][q] : x[b][q][c].
// Block = (c-tile 64, q-tile 64, b). Stage anti-diagonal O band in LDS
// (pitch 67 floats: odd pitch -> column shear reads are <=2-way bank alias).
// All global reads/writes are coalesced float4.
// ---------------------------------------------------------------------------
__global__ __launch_bounds__(256) void shear_kernel(const float* __restrict__ O,
                                                    const float* __restrict__ x,
                                                    float* __restrict__ y) {
    const int c0 = (int)blockIdx.x * 64;
    const int q0 = (int)blockIdx.y * 64;
    const int b  = (int)blockIdx.z;
    const int t  = (int)threadIdx.x;
    const float* xb = x + (size_t)b * SS * SS;
    float* yb       = y + (size_t)b * SS * SS;
    const int i0 = q0 + c0;

    if (i0 >= SS) {   // pure passthrough tile
#pragma unroll
        for (int k = 0; k < 4; ++k) {
            int task = t + 256 * k;
            int qq = task >> 4, c4 = (task & 15) * 4;
            size_t off = (size_t)(q0 + qq) * SS + c0 + c4;
            *reinterpret_cast<float4*>(yb + off) =
                *reinterpret_cast<const float4*>(xb + off);
        }
        return;
    }

    __shared__ float Os[127 * 67];
    const int nrows = min(127, SS - i0);
    const float* Ob = O + (size_t)b * SS * SS;

    for (int task = t; task < nrows * 16; task += 256) {
        int rr = task >> 4, q4 = (task & 15) * 4;
        float4 v = *reinterpret_cast<const float4*>(Ob + (size_t)(i0 + rr) * SS + q0 + q4);
        float* d = &Os[rr * 67 + q4];
        d[0] = v.x; d[1] = v.y; d[2] = v.z; d[3] = v.w;
    }
    __syncthreads();

#pragma unroll
    for (int k = 0; k < 4; ++k) {
        int task = t + 256 * k;
        int qq = task >> 4, c4 = (task & 15) * 4;
        int q = q0 + qq, c = c0 + c4;
        float4 o;
        if (i0 + qq + c4 + 3 < SS) {                 // whole float4 from O band
            o.x = Os[(qq + c4 + 0) * 67 + qq];
            o.y = Os[(qq + c4 + 1) * 67 + qq];
            o.z = Os[(qq + c4 + 2) * 67 + qq];
            o.w = Os[(qq + c4 + 3) * 67 + qq];
        } else {                                     // boundary mix
            float tmp[4];
#pragma unroll
            for (int kk = 0; kk < 4; ++kk) {
                tmp[kk] = (q + c + kk < SS) ? Os[(qq + c4 + kk) * 67 + qq]
                                            : xb[(size_t)q * SS + c + kk];
            }
            o = make_float4(tmp[0], tmp[1], tmp[2], tmp[3]);
        }
        *reinterpret_cast<float4*>(yb + (size_t)q * SS + c) = o;
    }
}

// ---------------------------------------------------------------------------
// f32 fallback (round-1), only if ws_size is tiny.
// ---------------------------------------------------------------------------
#define FTK 32
#define FWROW (TQ + 4)
__global__ __launch_bounds__(256) void diag_gemm_fallback(const float* __restrict__ x,
                                                          const float* __restrict__ W,
                                                          const float* __restrict__ bias,
                                                          float* __restrict__ y) {
    const int i  = (SS - 1) - (int)blockIdx.y;
    const int q0 = (int)blockIdx.x * TQ;
    if (q0 > i) return;
    __shared__ float Ds[FTK][BB];
    __shared__ float Ws[FTK][FWROW];
    const int tid = (int)threadIdx.x;
    const int qg  = tid & 31;
    const int bg  = tid >> 5;
    float acc[4][4];
#pragma unroll
    for (int a = 0; a < 4; ++a)
#pragma unroll
        for (int c = 0; c < 4; ++c) acc[a][c] = 0.0f;
    const float* Wi = W + (size_t)i * SS * SS;
    for (int r0 = 0; r0 <= i; r0 += FTK) {
        __syncthreads();
        {
            const int rr = tid >> 3;
            const int b4 = (tid & 7) * 4;
            const int r  = r0 + rr;
            float4 dv = make_float4(0.f, 0.f, 0.f, 0.f);
            if (r <= i) {
                const int col = i - r;
                dv.x = x[((size_t)(b4 + 0) * SS + r) * SS + col];
                dv.y = x[((size_t)(b4 + 1) * SS + r) * SS + col];
                dv.z = x[((size_t)(b4 + 2) * SS + r) * SS + col];
                dv.w = x[((size_t)(b4 + 3) * SS + r) * SS + col];
            }
            *reinterpret_cast<float4*>(&Ds[rr][b4]) = dv;
        }
#pragma unroll
        for (int l = 0; l < 4; ++l) {
            const int idx = tid + 256 * l;
            const int qL  = idx >> 3;
            const int rc  = idx & 7;
            const int r   = r0 + rc * 4;
            const float* wp = Wi + (size_t)(q0 + qL) * SS;
            float4 wv;
            if (r + 3 < SS) {
                wv = *reinterpret_cast<const float4*>(wp + r);
            } else {
                wv.x = wp[min(r + 0, SS - 1)];
                wv.y = wp[min(r + 1, SS - 1)];
                wv.z = wp[min(r + 2, SS - 1)];
                wv.w = wp[min(r + 3, SS - 1)];
            }
            Ws[rc * 4 + 0][qL] = wv.x;
            Ws[rc * 4 + 1][qL] = wv.y;
            Ws[rc * 4 + 2][qL] = wv.z;
            Ws[rc * 4 + 3][qL] = wv.w;
        }
        __syncthreads();
#pragma unroll
        for (int rr = 0; rr < FTK; ++rr) {
            const float4 d4 = *reinterpret_cast<const float4*>(&Ds[rr][bg * 4]);
            const float4 w4 = *reinterpret_cast<const float4*>(&Ws[rr][qg * 4]);
            acc[0][0] = fmaf(d4.x, w4.x, acc[0][0]); acc[0][1] = fmaf(d4.x, w4.y, acc[0][1]);
            acc[0][2] = fmaf(d4.x, w4.z, acc[0][2]); acc[0][3] = fmaf(d4.x, w4.w, acc[0][3]);
            acc[1][0] = fmaf(d4.y, w4.x, acc[1][0]); acc[1][1] = fmaf(d4.y, w4.y, acc[1][1]);
            acc[1][2] = fmaf(d4.y, w4.z, acc[1][2]); acc[1][3] = fmaf(d4.y, w4.w, acc[1][3]);
            acc[2][0] = fmaf(d4.z, w4.x, acc[2][0]); acc[2][1] = fmaf(d4.z, w4.y, acc[2][1]);
            acc[2][2] = fmaf(d4.z, w4.z, acc[2][2]); acc[2][3] = fmaf(d4.z, w4.w, acc[2][3]);
            acc[3][0] = fmaf(d4.w, w4.x, acc[3][0]); acc[3][1] = fmaf(d4.w, w4.y, acc[3][1]);
            acc[3][2] = fmaf(d4.w, w4.z, acc[3][2]); acc[3][3] = fmaf(d4.w, w4.w, acc[3][3]);
        }
    }
    const int qb = q0 + qg * 4;
    const float4 bv = *reinterpret_cast<const float4*>(bias + (size_t)i * SS + qb);
    const float bvals[4] = {bv.x, bv.y, bv.z, bv.w};
#pragma unroll
    for (int bi = 0; bi < 4; ++bi) {
        const int b = bg * 4 + bi;
        float* yb = y + (size_t)b * SS * SS;
#pragma unroll
        for (int qi = 0; qi < 4; ++qi) {
            const int q = qb + qi;
            if (q <= i) yb[(size_t)q * SS + (i - q)] = acc[bi][qi] + bvals[qi];
        }
    }
}

extern "C" void kernel_launch(void* const* d_in, const int* in_sizes, int n_in,
                              void* d_out, int out_size, void* d_ws, size_t ws_size,
                              hipStream_t stream) {
    const float* x    = (const float*)d_in[0];
    const float* W    = (const float*)d_in[1];
    const float* bias = (const float*)d_in[2];
    float* y          = (float*)d_out;

    const size_t D2_bytes = (size_t)64 * BB * SS * 16;            // 16 MiB
    const size_t O_bytes  = (size_t)BB * SS * SS * sizeof(float); // 32 MiB

    if (ws_size >= D2_bytes + O_bytes) {
        uint4* D2 = (uint4*)d_ws;
        float* O  = (float*)((char*)d_ws + D2_bytes);
        gather_kernel<<<dim3(64, 32), dim3(256), 0, stream>>>(x, D2);
        mfma_gemm_kernel<1><<<dim3(512, 4), dim3(256), 0, stream>>>(D2, W, bias, O);
        shear_kernel<<<dim3(8, 8, 32), dim3(256), 0, stream>>>(O, x, y);
    } else if (ws_size >= D2_bytes) {
        uint4* D2 = (uint4*)d_ws;
        copy_x_kernel<<<dim3(8192), dim3(256), 0, stream>>>(x, y);
        gather_kernel<<<dim3(64, 32), dim3(256), 0, stream>>>(x, D2);
        mfma_gemm_kernel<0><<<dim3(512, 4), dim3(256), 0, stream>>>(D2, W, bias, y);
    } else {
        copy_x_kernel<<<dim3(8192), dim3(256), 0, stream>>>(x, y);
        diag_gemm_fallback<<<dim3(SS / TQ, SS), dim3(256), 0, stream>>>(x, W, bias, y);
    }
}

// Round 4
// 107.901 us; speedup vs baseline: 2.1068x; 1.3543x over previous
//
#include <hip/hip_runtime.h>
#include <hip/hip_bf16.h>
#include <stdint.h>

#define SS 512
#define BB 32
#define TQ 128

typedef __bf16 bf16;
typedef __attribute__((ext_vector_type(8))) __bf16 bf16x8;
typedef __attribute__((ext_vector_type(4))) float f32x4;

// ---------------------------------------------------------------------------
// Kernel A (fallback paths only): y = x everywhere.
// ---------------------------------------------------------------------------
__global__ __launch_bounds__(256) void copy_x_kernel(const float* __restrict__ x,
                                                     float* __restrict__ y) {
    size_t idx = (size_t)blockIdx.x * 256 + threadIdx.x;
    reinterpret_cast<float4*>(y)[idx] = reinterpret_cast<const float4*>(x)[idx];
}

// ---------------------------------------------------------------------------
// Gather: D2[rb][b][i] (uint4 = 8 bf16, e-th elem = D[b, i, r=rb*8+e])
//   D[b,i,r] = x[b, r, i-r] if r <= i else 0
// ---------------------------------------------------------------------------
__global__ __launch_bounds__(256) void gather_kernel(const float* __restrict__ x,
                                                     uint4* __restrict__ D2) {
    const int rb = blockIdx.x;   // 0..63
    const int b  = blockIdx.y;   // 0..31
    __shared__ float xs[8][516];

    const int t = threadIdx.x;
    const float* xb = x + ((size_t)b * SS + rb * 8) * SS;
#pragma unroll
    for (int k = 0; k < 4; ++k) {
        int task = t + 256 * k;
        int c4 = task & 127;
        int e  = task >> 7;
        float4 v = *reinterpret_cast<const float4*>(xb + (size_t)e * SS + c4 * 4);
        *reinterpret_cast<float4*>(&xs[e][c4 * 4]) = v;
    }
    __syncthreads();

    const int r0 = rb * 8;
#pragma unroll
    for (int k = 0; k < 2; ++k) {
        int i = t + 256 * k;
        bf16x8 pack;
#pragma unroll
        for (int e = 0; e < 8; ++e) {
            int c  = i - (r0 + e);
            int cc = c < 0 ? 0 : c;
            float v = xs[e][cc];
            pack[e] = (c >= 0) ? (bf16)v : (bf16)0.0f;
        }
        D2[((size_t)rb * BB + b) * SS + i] = __builtin_bit_cast(uint4, pack);
    }
}

// ---------------------------------------------------------------------------
// MFMA GEMM. WRITE_O=1: out = O[b][i][q] coalesced (shear kernel finishes).
//           WRITE_O=0: out = y, direct anti-diagonal scatter (fallback).
// i-mapping: XCD-BALANCED. Dispatch round-robins bid across 8 XCDs, and K-work
// grows ~linearly with i, so give XCD x the runs {x, x+8, ...} of 8 consecutive
// i each: every XCD samples the heavy->light gradient uniformly (R3's
// contiguous-64 swizzle gave XCD0 2.36x the balanced load).
// ---------------------------------------------------------------------------
template <int WRITE_O>
__global__ __launch_bounds__(256) void mfma_gemm_kernel(const uint4* __restrict__ D2,
                                                        const float* __restrict__ W,
                                                        const float* __restrict__ bias,
                                                        float* __restrict__ out) {
    const int bid = (int)blockIdx.x;                 // 0..511
    const int xcd = bid & 7;
    const int m   = bid >> 3;                        // 0..63
    const int run = xcd + 8 * (m >> 3);              // run of 8 i's
    const int i   = (SS - 1) - (run * 8 + (m & 7));  // heavy i first on every XCD
    const int q0  = (int)blockIdx.y * TQ;
    if (q0 > i) return;

    const int qmax = ((i >> 4) + 1) * 16;
    const int qhi  = min(qmax - q0, TQ);
    const int nk   = (i >> 5) + 1;

    __shared__ bf16 Bs[TQ][40];

    const int t    = (int)threadIdx.x;
    const int lane = t & 63;
    const int w    = t >> 6;
    const int l15  = lane & 15;
    const int lg   = lane >> 4;

    f32x4 acc[2][2];
#pragma unroll
    for (int n = 0; n < 2; ++n)
#pragma unroll
        for (int m2 = 0; m2 < 2; ++m2) acc[n][m2] = (f32x4)0.0f;

    const float* Wi  = W + (size_t)i * SS * SS;
    const uint4* D2i = D2 + i;

    for (int kk = 0; kk < nk; ++kk) {
        const int r0 = kk * 32;
        __syncthreads();

#pragma unroll
        for (int s = 0; s < 2; ++s) {
            int task = t + 256 * s;
            if (task < qhi * 4) {
                int qq = task >> 2;
                int ch = task & 3;
                const float* wp = Wi + (size_t)(q0 + qq) * SS + r0 + ch * 8;
                float4 v0 = *reinterpret_cast<const float4*>(wp);
                float4 v1 = *reinterpret_cast<const float4*>(wp + 4);
                bf16x8 pk;
                pk[0] = (bf16)v0.x; pk[1] = (bf16)v0.y; pk[2] = (bf16)v0.z; pk[3] = (bf16)v0.w;
                pk[4] = (bf16)v1.x; pk[5] = (bf16)v1.y; pk[6] = (bf16)v1.z; pk[7] = (bf16)v1.w;
                *reinterpret_cast<uint4*>(&Bs[qq][ch * 8]) = __builtin_bit_cast(uint4, pk);
            }
        }

        const uint4 a0 = D2i[(size_t)(((r0 >> 3) + lg) * BB + l15) * SS];
        const uint4 a1 = D2i[(size_t)(((r0 >> 3) + lg) * BB + 16 + l15) * SS];

        __syncthreads();

        const bf16x8 aa0 = __builtin_bit_cast(bf16x8, a0);
        const bf16x8 aa1 = __builtin_bit_cast(bf16x8, a1);
#pragma unroll
        for (int n = 0; n < 2; ++n) {
            const int f  = n * 4 + w;
            const int qf = q0 + f * 16;
            if (qf <= i) {
                uint4 bv = *reinterpret_cast<const uint4*>(&Bs[f * 16 + l15][lg * 8]);
                bf16x8 bb = __builtin_bit_cast(bf16x8, bv);
                acc[n][0] = __builtin_amdgcn_mfma_f32_16x16x32_bf16(aa0, bb, acc[n][0], 0, 0, 0);
                acc[n][1] = __builtin_amdgcn_mfma_f32_16x16x32_bf16(aa1, bb, acc[n][1], 0, 0, 0);
            }
        }
    }

    // C/D layout: col(q)=lane&15, row(b)=(lane>>4)*4+reg
#pragma unroll
    for (int n = 0; n < 2; ++n) {
        const int f  = n * 4 + w;
        const int qf = q0 + f * 16;
        if (qf <= i) {
            const int q  = qf + l15;
            const float bv = bias[(size_t)i * SS + q];
            if (WRITE_O) {
#pragma unroll
                for (int m2 = 0; m2 < 2; ++m2)
#pragma unroll
                    for (int v = 0; v < 4; ++v) {
                        const int b = m2 * 16 + lg * 4 + v;
                        out[((size_t)b * SS + i) * SS + q] = acc[n][m2][v] + bv;
                    }
            } else {
                const bool ok = (q <= i);
#pragma unroll
                for (int m2 = 0; m2 < 2; ++m2)
#pragma unroll
                    for (int v = 0; v < 4; ++v) {
                        const int b = m2 * 16 + lg * 4 + v;
                        if (ok) out[((size_t)b * SS + q) * SS + (i - q)] = acc[n][m2][v] + bv;
                    }
            }
        }
    }
}

// ---------------------------------------------------------------------------
// Shear: y[b][q][c] = (q+c < S) ? O[b][q+c][q] : x[b][q][c].
// ---------------------------------------------------------------------------
__global__ __launch_bounds__(256) void shear_kernel(const float* __restrict__ O,
                                                    const float* __restrict__ x,
                                                    float* __restrict__ y) {
    const int c0 = (int)blockIdx.x * 64;
    const int q0 = (int)blockIdx.y * 64;
    const int b  = (int)blockIdx.z;
    const int t  = (int)threadIdx.x;
    const float* xb = x + (size_t)b * SS * SS;
    float* yb       = y + (size_t)b * SS * SS;
    const int i0 = q0 + c0;

    if (i0 >= SS) {   // pure passthrough tile
#pragma unroll
        for (int k = 0; k < 4; ++k) {
            int task = t + 256 * k;
            int qq = task >> 4, c4 = (task & 15) * 4;
            size_t off = (size_t)(q0 + qq) * SS + c0 + c4;
            *reinterpret_cast<float4*>(yb + off) =
                *reinterpret_cast<const float4*>(xb + off);
        }
        return;
    }

    __shared__ float Os[127 * 67];
    const int nrows = min(127, SS - i0);
    const float* Ob = O + (size_t)b * SS * SS;

    for (int task = t; task < nrows * 16; task += 256) {
        int rr = task >> 4, q4 = (task & 15) * 4;
        float4 v = *reinterpret_cast<const float4*>(Ob + (size_t)(i0 + rr) * SS + q0 + q4);
        float* d = &Os[rr * 67 + q4];
        d[0] = v.x; d[1] = v.y; d[2] = v.z; d[3] = v.w;
    }
    __syncthreads();

#pragma unroll
    for (int k = 0; k < 4; ++k) {
        int task = t + 256 * k;
        int qq = task >> 4, c4 = (task & 15) * 4;
        int q = q0 + qq, c = c0 + c4;
        float4 o;
        if (i0 + qq + c4 + 3 < SS) {
            o.x = Os[(qq + c4 + 0) * 67 + qq];
            o.y = Os[(qq + c4 + 1) * 67 + qq];
            o.z = Os[(qq + c4 + 2) * 67 + qq];
            o.w = Os[(qq + c4 + 3) * 67 + qq];
        } else {
            float tmp[4];
#pragma unroll
            for (int kk = 0; kk < 4; ++kk) {
                tmp[kk] = (q + c + kk < SS) ? Os[(qq + c4 + kk) * 67 + qq]
                                            : xb[(size_t)q * SS + c + kk];
            }
            o = make_float4(tmp[0], tmp[1], tmp[2], tmp[3]);
        }
        *reinterpret_cast<float4*>(yb + (size_t)q * SS + c) = o;
    }
}

// ---------------------------------------------------------------------------
// f32 fallback (round-1), only if ws_size is tiny.
// ---------------------------------------------------------------------------
#define FTK 32
#define FWROW (TQ + 4)
__global__ __launch_bounds__(256) void diag_gemm_fallback(const float* __restrict__ x,
                                                          const float* __restrict__ W,
                                                          const float* __restrict__ bias,
                                                          float* __restrict__ y) {
    const int i  = (SS - 1) - (int)blockIdx.y;
    const int q0 = (int)blockIdx.x * TQ;
    if (q0 > i) return;
    __shared__ float Ds[FTK][BB];
    __shared__ float Ws[FTK][FWROW];
    const int tid = (int)threadIdx.x;
    const int qg  = tid & 31;
    const int bg  = tid >> 5;
    float acc[4][4];
#pragma unroll
    for (int a = 0; a < 4; ++a)
#pragma unroll
        for (int c = 0; c < 4; ++c) acc[a][c] = 0.0f;
    const float* Wi = W + (size_t)i * SS * SS;
    for (int r0 = 0; r0 <= i; r0 += FTK) {
        __syncthreads();
        {
            const int rr = tid >> 3;
            const int b4 = (tid & 7) * 4;
            const int r  = r0 + rr;
            float4 dv = make_float4(0.f, 0.f, 0.f, 0.f);
            if (r <= i) {
                const int col = i - r;
                dv.x = x[((size_t)(b4 + 0) * SS + r) * SS + col];
                dv.y = x[((size_t)(b4 + 1) * SS + r) * SS + col];
                dv.z = x[((size_t)(b4 + 2) * SS + r) * SS + col];
                dv.w = x[((size_t)(b4 + 3) * SS + r) * SS + col];
            }
            *reinterpret_cast<float4*>(&Ds[rr][b4]) = dv;
        }
#pragma unroll
        for (int l = 0; l < 4; ++l) {
            const int idx = tid + 256 * l;
            const int qL  = idx >> 3;
            const int rc  = idx & 7;
            const int r   = r0 + rc * 4;
            const float* wp = Wi + (size_t)(q0 + qL) * SS;
            float4 wv;
            if (r + 3 < SS) {
                wv = *reinterpret_cast<const float4*>(wp + r);
            } else {
                wv.x = wp[min(r + 0, SS - 1)];
                wv.y = wp[min(r + 1, SS - 1)];
                wv.z = wp[min(r + 2, SS - 1)];
                wv.w = wp[min(r + 3, SS - 1)];
            }
            Ws[rc * 4 + 0][qL] = wv.x;
            Ws[rc * 4 + 1][qL] = wv.y;
            Ws[rc * 4 + 2][qL] = wv.z;
            Ws[rc * 4 + 3][qL] = wv.w;
        }
        __syncthreads();
#pragma unroll
        for (int rr = 0; rr < FTK; ++rr) {
            const float4 d4 = *reinterpret_cast<const float4*>(&Ds[rr][bg * 4]);
            const float4 w4 = *reinterpret_cast<const float4*>(&Ws[rr][qg * 4]);
            acc[0][0] = fmaf(d4.x, w4.x, acc[0][0]); acc[0][1] = fmaf(d4.x, w4.y, acc[0][1]);
            acc[0][2] = fmaf(d4.x, w4.z, acc[0][2]); acc[0][3] = fmaf(d4.x, w4.w, acc[0][3]);
            acc[1][0] = fmaf(d4.y, w4.x, acc[1][0]); acc[1][1] = fmaf(d4.y, w4.y, acc[1][1]);
            acc[1][2] = fmaf(d4.y, w4.z, acc[1][2]); acc[1][3] = fmaf(d4.y, w4.w, acc[1][3]);
            acc[2][0] = fmaf(d4.z, w4.x, acc[2][0]); acc[2][1] = fmaf(d4.z, w4.y, acc[2][1]);
            acc[2][2] = fmaf(d4.z, w4.z, acc[2][2]); acc[2][3] = fmaf(d4.z, w4.w, acc[2][3]);
            acc[3][0] = fmaf(d4.w, w4.x, acc[3][0]); acc[3][1] = fmaf(d4.w, w4.y, acc[3][1]);
            acc[3][2] = fmaf(d4.w, w4.z, acc[3][2]); acc[3][3] = fmaf(d4.w, w4.w, acc[3][3]);
        }
    }
    const int qb = q0 + qg * 4;
    const float4 bv = *reinterpret_cast<const float4*>(bias + (size_t)i * SS + qb);
    const float bvals[4] = {bv.x, bv.y, bv.z, bv.w};
#pragma unroll
    for (int bi = 0; bi < 4; ++bi) {
        const int b = bg * 4 + bi;
        float* yb = y + (size_t)b * SS * SS;
#pragma unroll
        for (int qi = 0; qi < 4; ++qi) {
            const int q = qb + qi;
            if (q <= i) yb[(size_t)q * SS + (i - q)] = acc[bi][qi] + bvals[qi];
        }
    }
}

extern "C" void kernel_launch(void* const* d_in, const int* in_sizes, int n_in,
                              void* d_out, int out_size, void* d_ws, size_t ws_size,
                              hipStream_t stream) {
    const float* x    = (const float*)d_in[0];
    const float* W    = (const float*)d_in[1];
    const float* bias = (const float*)d_in[2];
    float* y          = (float*)d_out;

    const size_t D2_bytes = (size_t)64 * BB * SS * 16;            // 16 MiB
    const size_t O_bytes  = (size_t)BB * SS * SS * sizeof(float); // 32 MiB

    if (ws_size >= D2_bytes + O_bytes) {
        uint4* D2 = (uint4*)d_ws;
        float* O  = (float*)((char*)d_ws + D2_bytes);
        gather_kernel<<<dim3(64, 32), dim3(256), 0, stream>>>(x, D2);
        mfma_gemm_kernel<1><<<dim3(512, 4), dim3(256), 0, stream>>>(D2, W, bias, O);
        shear_kernel<<<dim3(8, 8, 32), dim3(256), 0, stream>>>(O, x, y);
    } else if (ws_size >= D2_bytes) {
        uint4* D2 = (uint4*)d_ws;
        copy_x_kernel<<<dim3(8192), dim3(256), 0, stream>>>(x, y);
        gather_kernel<<<dim3(64, 32), dim3(256), 0, stream>>>(x, D2);
        mfma_gemm_kernel<0><<<dim3(512, 4), dim3(256), 0, stream>>>(D2, W, bias, y);
    } else {
        copy_x_kernel<<<dim3(8192), dim3(256), 0, stream>>>(x, y);
        diag_gemm_fallback<<<dim3(SS / TQ, SS), dim3(256), 0, stream>>>(x, W, bias, y);
    }
}

// Round 5
// 95.311 us; speedup vs baseline: 2.3851x; 1.1321x over previous
//
#include <hip/hip_runtime.h>
#include <hip/hip_bf16.h>
#include <stdint.h>

#define SS 512
#define BB 32
#define TQ 128

typedef __bf16 bf16;
typedef __attribute__((ext_vector_type(8))) __bf16 bf16x8;
typedef __attribute__((ext_vector_type(4))) float f32x4;

// ---------------------------------------------------------------------------
// Kernel A (fallback paths only): y = x everywhere.
// ---------------------------------------------------------------------------
__global__ __launch_bounds__(256) void copy_x_kernel(const float* __restrict__ x,
                                                     float* __restrict__ y) {
    size_t idx = (size_t)blockIdx.x * 256 + threadIdx.x;
    reinterpret_cast<float4*>(y)[idx] = reinterpret_cast<const float4*>(x)[idx];
}

// ---------------------------------------------------------------------------
// Gather: D2[rb][b][i] (uint4 = 8 bf16, e-th elem = D[b, i, r=rb*8+e])
//   D[b,i,r] = x[b, r, i-r] if r <= i else 0
// ---------------------------------------------------------------------------
__global__ __launch_bounds__(256) void gather_kernel(const float* __restrict__ x,
                                                     uint4* __restrict__ D2) {
    const int rb = blockIdx.x;   // 0..63
    const int b  = blockIdx.y;   // 0..31
    __shared__ float xs[8][516];

    const int t = threadIdx.x;
    const float* xb = x + ((size_t)b * SS + rb * 8) * SS;
#pragma unroll
    for (int k = 0; k < 4; ++k) {
        int task = t + 256 * k;
        int c4 = task & 127;
        int e  = task >> 7;
        float4 v = *reinterpret_cast<const float4*>(xb + (size_t)e * SS + c4 * 4);
        *reinterpret_cast<float4*>(&xs[e][c4 * 4]) = v;
    }
    __syncthreads();

    const int r0 = rb * 8;
#pragma unroll
    for (int k = 0; k < 2; ++k) {
        int i = t + 256 * k;
        bf16x8 pack;
#pragma unroll
        for (int e = 0; e < 8; ++e) {
            int c  = i - (r0 + e);
            int cc = c < 0 ? 0 : c;
            float v = xs[e][cc];
            pack[e] = (c >= 0) ? (bf16)v : (bf16)0.0f;
        }
        D2[((size_t)rb * BB + b) * SS + i] = __builtin_bit_cast(uint4, pack);
    }
}

// ---------------------------------------------------------------------------
// MFMA GEMM, software-pipelined: per K-step, prefetch W(k+1)/A(k+1) into regs,
// MFMA(k) from LDS buf[cur] (hides global latency), cvt+ds_write(k+1) to
// buf[cur^1], ONE barrier. i-mapping XCD-balanced (runs of 8, heavy-first).
// ---------------------------------------------------------------------------
template <int WRITE_O>
__global__ __launch_bounds__(256) void mfma_gemm_kernel(const uint4* __restrict__ D2,
                                                        const float* __restrict__ W,
                                                        const float* __restrict__ bias,
                                                        float* __restrict__ out) {
    const int bid = (int)blockIdx.x;                 // 0..511
    const int xcd = bid & 7;
    const int m   = bid >> 3;                        // 0..63
    const int run = xcd + 8 * (m >> 3);
    const int i   = (SS - 1) - (run * 8 + (m & 7));
    const int q0  = (int)blockIdx.y * TQ;
    if (q0 > i) return;

    const int qmax = ((i >> 4) + 1) * 16;
    const int qhi  = min(qmax - q0, TQ);
    const int nk   = (i >> 5) + 1;

    __shared__ bf16 Bs[2][TQ][40];

    const int t    = (int)threadIdx.x;
    const int lane = t & 63;
    const int w    = t >> 6;
    const int l15  = lane & 15;
    const int lg   = lane >> 4;

    f32x4 acc[2][2];
#pragma unroll
    for (int n = 0; n < 2; ++n)
#pragma unroll
        for (int m2 = 0; m2 < 2; ++m2) acc[n][m2] = (f32x4)0.0f;

    const float* Wi  = W + (size_t)i * SS * SS;
    const uint4* D2i = D2 + i;

    // staging task decode (2 tasks/thread)
    const int qq0 = t >> 2,          ch0 = t & 3;
    const int qq1 = (t + 256) >> 2,  ch1 = (t + 256) & 3;
    const bool st0 = (t < qhi * 4);
    const bool st1 = (t + 256 < qhi * 4);

    float4 w0a, w0b, w1a, w1b;        // prefetched W regs (2 tasks x 32B)
    uint4  a0c, a1c, a0n, a1n;        // A frags, current / next

    auto issueW = [&](int kk) {
        const int r0 = kk * 32;
        if (st0) {
            const float* wp = Wi + (size_t)(q0 + qq0) * SS + r0 + ch0 * 8;
            w0a = *reinterpret_cast<const float4*>(wp);
            w0b = *reinterpret_cast<const float4*>(wp + 4);
        }
        if (st1) {
            const float* wp = Wi + (size_t)(q0 + qq1) * SS + r0 + ch1 * 8;
            w1a = *reinterpret_cast<const float4*>(wp);
            w1b = *reinterpret_cast<const float4*>(wp + 4);
        }
    };
    auto issueA = [&](int kk, uint4& a0, uint4& a1) {
        const int rb = (kk * 32) >> 3;
        a0 = D2i[(size_t)((rb + lg) * BB + l15) * SS];
        a1 = D2i[(size_t)((rb + lg) * BB + 16 + l15) * SS];
    };
    auto writeB = [&](int buf) {
        if (st0) {
            bf16x8 pk;
            pk[0] = (bf16)w0a.x; pk[1] = (bf16)w0a.y; pk[2] = (bf16)w0a.z; pk[3] = (bf16)w0a.w;
            pk[4] = (bf16)w0b.x; pk[5] = (bf16)w0b.y; pk[6] = (bf16)w0b.z; pk[7] = (bf16)w0b.w;
            *reinterpret_cast<uint4*>(&Bs[buf][qq0][ch0 * 8]) = __builtin_bit_cast(uint4, pk);
        }
        if (st1) {
            bf16x8 pk;
            pk[0] = (bf16)w1a.x; pk[1] = (bf16)w1a.y; pk[2] = (bf16)w1a.z; pk[3] = (bf16)w1a.w;
            pk[4] = (bf16)w1b.x; pk[5] = (bf16)w1b.y; pk[6] = (bf16)w1b.z; pk[7] = (bf16)w1b.w;
            *reinterpret_cast<uint4*>(&Bs[buf][qq1][ch1 * 8]) = __builtin_bit_cast(uint4, pk);
        }
    };

    // prologue: stage k=0
    issueW(0);
    issueA(0, a0c, a1c);
    writeB(0);
    __syncthreads();

    int cur = 0;
    for (int kk = 0; kk < nk; ++kk) {
        const bool more = (kk + 1 < nk);
        if (more) {
            issueW(kk + 1);              // global loads in flight across MFMA phase
            issueA(kk + 1, a0n, a1n);
        }

        const bf16x8 aa0 = __builtin_bit_cast(bf16x8, a0c);
        const bf16x8 aa1 = __builtin_bit_cast(bf16x8, a1c);
#pragma unroll
        for (int n = 0; n < 2; ++n) {
            const int f  = n * 4 + w;
            const int qf = q0 + f * 16;
            if (qf <= i) {
                uint4 bv = *reinterpret_cast<const uint4*>(&Bs[cur][f * 16 + l15][lg * 8]);
                bf16x8 bb = __builtin_bit_cast(bf16x8, bv);
                acc[n][0] = __builtin_amdgcn_mfma_f32_16x16x32_bf16(aa0, bb, acc[n][0], 0, 0, 0);
                acc[n][1] = __builtin_amdgcn_mfma_f32_16x16x32_bf16(aa1, bb, acc[n][1], 0, 0, 0);
            }
        }

        if (more) writeB(cur ^ 1);       // waits the W loads, fast LDS writes
        __syncthreads();                  // one barrier per K-step
        a0c = a0n; a1c = a1n;
        cur ^= 1;
    }

    // epilogue: C/D layout col(q)=lane&15, row(b)=(lane>>4)*4+reg
#pragma unroll
    for (int n = 0; n < 2; ++n) {
        const int f  = n * 4 + w;
        const int qf = q0 + f * 16;
        if (qf <= i) {
            const int q  = qf + l15;
            const float bv = bias[(size_t)i * SS + q];
            if (WRITE_O) {
#pragma unroll
                for (int m2 = 0; m2 < 2; ++m2)
#pragma unroll
                    for (int v = 0; v < 4; ++v) {
                        const int b = m2 * 16 + lg * 4 + v;
                        out[((size_t)b * SS + i) * SS + q] = acc[n][m2][v] + bv;
                    }
            } else {
                const bool ok = (q <= i);
#pragma unroll
                for (int m2 = 0; m2 < 2; ++m2)
#pragma unroll
                    for (int v = 0; v < 4; ++v) {
                        const int b = m2 * 16 + lg * 4 + v;
                        if (ok) out[((size_t)b * SS + q) * SS + (i - q)] = acc[n][m2][v] + bv;
                    }
            }
        }
    }
}

// ---------------------------------------------------------------------------
// Shear: y[b][q][c] = (q+c < S) ? O[b][q+c][q] : x[b][q][c].
// ---------------------------------------------------------------------------
__global__ __launch_bounds__(256) void shear_kernel(const float* __restrict__ O,
                                                    const float* __restrict__ x,
                                                    float* __restrict__ y) {
    const int c0 = (int)blockIdx.x * 64;
    const int q0 = (int)blockIdx.y * 64;
    const int b  = (int)blockIdx.z;
    const int t  = (int)threadIdx.x;
    const float* xb = x + (size_t)b * SS * SS;
    float* yb       = y + (size_t)b * SS * SS;
    const int i0 = q0 + c0;

    if (i0 >= SS) {   // pure passthrough tile
#pragma unroll
        for (int k = 0; k < 4; ++k) {
            int task = t + 256 * k;
            int qq = task >> 4, c4 = (task & 15) * 4;
            size_t off = (size_t)(q0 + qq) * SS + c0 + c4;
            *reinterpret_cast<float4*>(yb + off) =
                *reinterpret_cast<const float4*>(xb + off);
        }
        return;
    }

    __shared__ float Os[127 * 67];
    const int nrows = min(127, SS - i0);
    const float* Ob = O + (size_t)b * SS * SS;

    for (int task = t; task < nrows * 16; task += 256) {
        int rr = task >> 4, q4 = (task & 15) * 4;
        float4 v = *reinterpret_cast<const float4*>(Ob + (size_t)(i0 + rr) * SS + q0 + q4);
        float* d = &Os[rr * 67 + q4];
        d[0] = v.x; d[1] = v.y; d[2] = v.z; d[3] = v.w;
    }
    __syncthreads();

#pragma unroll
    for (int k = 0; k < 4; ++k) {
        int task = t + 256 * k;
        int qq = task >> 4, c4 = (task & 15) * 4;
        int q = q0 + qq, c = c0 + c4;
        float4 o;
        if (i0 + qq + c4 + 3 < SS) {
            o.x = Os[(qq + c4 + 0) * 67 + qq];
            o.y = Os[(qq + c4 + 1) * 67 + qq];
            o.z = Os[(qq + c4 + 2) * 67 + qq];
            o.w = Os[(qq + c4 + 3) * 67 + qq];
        } else {
            float tmp[4];
#pragma unroll
            for (int kk = 0; kk < 4; ++kk) {
                tmp[kk] = (q + c + kk < SS) ? Os[(qq + c4 + kk) * 67 + qq]
                                            : xb[(size_t)q * SS + c + kk];
            }
            o = make_float4(tmp[0], tmp[1], tmp[2], tmp[3]);
        }
        *reinterpret_cast<float4*>(yb + (size_t)q * SS + c) = o;
    }
}

// ---------------------------------------------------------------------------
// f32 fallback (round-1), only if ws_size is tiny.
// ---------------------------------------------------------------------------
#define FTK 32
#define FWROW (TQ + 4)
__global__ __launch_bounds__(256) void diag_gemm_fallback(const float* __restrict__ x,
                                                          const float* __restrict__ W,
                                                          const float* __restrict__ bias,
                                                          float* __restrict__ y) {
    const int i  = (SS - 1) - (int)blockIdx.y;
    const int q0 = (int)blockIdx.x * TQ;
    if (q0 > i) return;
    __shared__ float Ds[FTK][BB];
    __shared__ float Ws[FTK][FWROW];
    const int tid = (int)threadIdx.x;
    const int qg  = tid & 31;
    const int bg  = tid >> 5;
    float acc[4][4];
#pragma unroll
    for (int a = 0; a < 4; ++a)
#pragma unroll
        for (int c = 0; c < 4; ++c) acc[a][c] = 0.0f;
    const float* Wi = W + (size_t)i * SS * SS;
    for (int r0 = 0; r0 <= i; r0 += FTK) {
        __syncthreads();
        {
            const int rr = tid >> 3;
            const int b4 = (tid & 7) * 4;
            const int r  = r0 + rr;
            float4 dv = make_float4(0.f, 0.f, 0.f, 0.f);
            if (r <= i) {
                const int col = i - r;
                dv.x = x[((size_t)(b4 + 0) * SS + r) * SS + col];
                dv.y = x[((size_t)(b4 + 1) * SS + r) * SS + col];
                dv.z = x[((size_t)(b4 + 2) * SS + r) * SS + col];
                dv.w = x[((size_t)(b4 + 3) * SS + r) * SS + col];
            }
            *reinterpret_cast<float4*>(&Ds[rr][b4]) = dv;
        }
#pragma unroll
        for (int l = 0; l < 4; ++l) {
            const int idx = tid + 256 * l;
            const int qL  = idx >> 3;
            const int rc  = idx & 7;
            const int r   = r0 + rc * 4;
            const float* wp = Wi + (size_t)(q0 + qL) * SS;
            float4 wv;
            if (r + 3 < SS) {
                wv = *reinterpret_cast<const float4*>(wp + r);
            } else {
                wv.x = wp[min(r + 0, SS - 1)];
                wv.y = wp[min(r + 1, SS - 1)];
                wv.z = wp[min(r + 2, SS - 1)];
                wv.w = wp[min(r + 3, SS - 1)];
            }
            Ws[rc * 4 + 0][qL] = wv.x;
            Ws[rc * 4 + 1][qL] = wv.y;
            Ws[rc * 4 + 2][qL] = wv.z;
            Ws[rc * 4 + 3][qL] = wv.w;
        }
        __syncthreads();
#pragma unroll
        for (int rr = 0; rr < FTK; ++rr) {
            const float4 d4 = *reinterpret_cast<const float4*>(&Ds[rr][bg * 4]);
            const float4 w4 = *reinterpret_cast<const float4*>(&Ws[rr][qg * 4]);
            acc[0][0] = fmaf(d4.x, w4.x, acc[0][0]); acc[0][1] = fmaf(d4.x, w4.y, acc[0][1]);
            acc[0][2] = fmaf(d4.x, w4.z, acc[0][2]); acc[0][3] = fmaf(d4.x, w4.w, acc[0][3]);
            acc[1][0] = fmaf(d4.y, w4.x, acc[1][0]); acc[1][1] = fmaf(d4.y, w4.y, acc[1][1]);
            acc[1][2] = fmaf(d4.y, w4.z, acc[1][2]); acc[1][3] = fmaf(d4.y, w4.w, acc[1][3]);
            acc[2][0] = fmaf(d4.z, w4.x, acc[2][0]); acc[2][1] = fmaf(d4.z, w4.y, acc[2][1]);
            acc[2][2] = fmaf(d4.z, w4.z, acc[2][2]); acc[2][3] = fmaf(d4.z, w4.w, acc[2][3]);
            acc[3][0] = fmaf(d4.w, w4.x, acc[3][0]); acc[3][1] = fmaf(d4.w, w4.y, acc[3][1]);
            acc[3][2] = fmaf(d4.w, w4.z, acc[3][2]); acc[3][3] = fmaf(d4.w, w4.w, acc[3][3]);
        }
    }
    const int qb = q0 + qg * 4;
    const float4 bv = *reinterpret_cast<const float4*>(bias + (size_t)i * SS + qb);
    const float bvals[4] = {bv.x, bv.y, bv.z, bv.w};
#pragma unroll
    for (int bi = 0; bi < 4; ++bi) {
        const int b = bg * 4 + bi;
        float* yb = y + (size_t)b * SS * SS;
#pragma unroll
        for (int qi = 0; qi < 4; ++qi) {
            const int q = qb + qi;
            if (q <= i) yb[(size_t)q * SS + (i - q)] = acc[bi][qi] + bvals[qi];
        }
    }
}

extern "C" void kernel_launch(void* const* d_in, const int* in_sizes, int n_in,
                              void* d_out, int out_size, void* d_ws, size_t ws_size,
                              hipStream_t stream) {
    const float* x    = (const float*)d_in[0];
    const float* W    = (const float*)d_in[1];
    const float* bias = (const float*)d_in[2];
    float* y          = (float*)d_out;

    const size_t D2_bytes = (size_t)64 * BB * SS * 16;            // 16 MiB
    const size_t O_bytes  = (size_t)BB * SS * SS * sizeof(float); // 32 MiB

    if (ws_size >= D2_bytes + O_bytes) {
        uint4* D2 = (uint4*)d_ws;
        float* O  = (float*)((char*)d_ws + D2_bytes);
        gather_kernel<<<dim3(64, 32), dim3(256), 0, stream>>>(x, D2);
        mfma_gemm_kernel<1><<<dim3(512, 4), dim3(256), 0, stream>>>(D2, W, bias, O);
        shear_kernel<<<dim3(8, 8, 32), dim3(256), 0, stream>>>(O, x, y);
    } else if (ws_size >= D2_bytes) {
        uint4* D2 = (uint4*)d_ws;
        copy_x_kernel<<<dim3(8192), dim3(256), 0, stream>>>(x, y);
        gather_kernel<<<dim3(64, 32), dim3(256), 0, stream>>>(x, D2);
        mfma_gemm_kernel<0><<<dim3(512, 4), dim3(256), 0, stream>>>(D2, W, bias, y);
    } else {
        copy_x_kernel<<<dim3(8192), dim3(256), 0, stream>>>(x, y);
        diag_gemm_fallback<<<dim3(SS / TQ, SS), dim3(256), 0, stream>>>(x, W, bias, y);
    }
}